// Round 1
// baseline (232.906 us; speedup 1.0000x reference)
//
#include <hip/hip_runtime.h>
#include <stdint.h>

// ---------------------------------------------------------------------------
// MultiExpertMultiHeadAttention  (B=8,S=512,D=256,E=8,H=4,DH=64)
// Pipeline: cast->bf16, QKV GEMMs (bf16 MFMA), flash attention, output GEMM.
// Workspace usage: 77,594,624 bytes.
// ---------------------------------------------------------------------------

typedef __bf16 bf16x8 __attribute__((ext_vector_type(8)));
typedef float f32x4 __attribute__((ext_vector_type(4)));
typedef unsigned short u16x8 __attribute__((ext_vector_type(8)));
typedef unsigned short u16x4 __attribute__((ext_vector_type(4)));

#define MFMA16(a, b, c) __builtin_amdgcn_mfma_f32_16x16x32_bf16(a, b, c, 0, 0, 0)

__device__ __forceinline__ unsigned short f2bf(float x) {
    uint32_t u = __builtin_bit_cast(uint32_t, x);
    u += 0x7FFFu + ((u >> 16) & 1u);      // round-to-nearest-even
    return (unsigned short)(u >> 16);
}

// --------------------------- cast activations ------------------------------
__global__ __launch_bounds__(256) void cast_act_kern(
        const float* __restrict__ s0, const float* __restrict__ s1,
        const float* __restrict__ s2,
        unsigned short* __restrict__ o0, unsigned short* __restrict__ o1,
        unsigned short* __restrict__ o2) {
    int z = blockIdx.z;
    const float* s = (z == 0) ? s0 : (z == 1) ? s1 : s2;
    unsigned short* o = (z == 0) ? o0 : (z == 1) ? o1 : o2;
    int i = (blockIdx.x * 256 + threadIdx.x) * 4;
    float4 f = *(const float4*)&s[i];
    u16x4 r;
    r[0] = f2bf(f.x); r[1] = f2bf(f.y); r[2] = f2bf(f.z); r[3] = f2bf(f.w);
    *(u16x4*)&o[i] = r;
}

// ----------------------- transpose + cast weights --------------------------
// W [256][2048] f32  ->  Wt [2048][256] bf16
__global__ __launch_bounds__(256) void cast_wt_kern(
        const float* __restrict__ W0, const float* __restrict__ W1,
        const float* __restrict__ W2, const float* __restrict__ W3,
        unsigned short* __restrict__ T0, unsigned short* __restrict__ T1,
        unsigned short* __restrict__ T2, unsigned short* __restrict__ T3) {
    int z = blockIdx.z;
    const float* W = (z == 0) ? W0 : (z == 1) ? W1 : (z == 2) ? W2 : W3;
    unsigned short* T = (z == 0) ? T0 : (z == 1) ? T1 : (z == 2) ? T2 : T3;
    __shared__ float tile[32][33];
    int t = threadIdx.x;
    int tr = t >> 3, tc = (t & 7) * 4;
    int c0 = blockIdx.x * 32, r0 = blockIdx.y * 32;
    float4 v = *(const float4*)&W[(r0 + tr) * 2048 + c0 + tc];
    tile[tr][tc + 0] = v.x; tile[tr][tc + 1] = v.y;
    tile[tr][tc + 2] = v.z; tile[tr][tc + 3] = v.w;
    __syncthreads();
    u16x4 o;
    o[0] = f2bf(tile[tc + 0][tr]); o[1] = f2bf(tile[tc + 1][tr]);
    o[2] = f2bf(tile[tc + 2][tr]); o[3] = f2bf(tile[tc + 3][tr]);
    *(u16x4*)&T[(c0 + tr) * 256 + r0 + tc] = o;
}

// ------------------------------- GEMM --------------------------------------
// C[M x 2048] = A[M x 256](bf16) * B,  B given as Bt[2048][256] (bf16, B^T).
// 128x128 tile, BK=32, 256 threads (4 waves, 2x2 wave grid, 64x64 per wave).
template <bool OUTBF>
__global__ __launch_bounds__(256) void gemm_kern(
        const unsigned short* __restrict__ A, const unsigned short* __restrict__ Bt,
        void* __restrict__ Cp, float scale) {
    __shared__ unsigned short Asl[128 * 40];   // stride 40 ushorts = 80B (16B-aligned rows)
    __shared__ unsigned short Bsl[128 * 40];
    const int t = threadIdx.x, l = t & 63, w = t >> 6;
    const int li = l & 15, g = l >> 4;
    const int wr = w >> 1, wc = w & 1;
    const int rowA = blockIdx.y * 128, colB = blockIdx.x * 128;
    f32x4 acc[4][4];
#pragma unroll
    for (int m = 0; m < 4; ++m)
#pragma unroll
        for (int n = 0; n < 4; ++n) acc[m][n] = (f32x4){0.f, 0.f, 0.f, 0.f};

    for (int kk = 0; kk < 8; ++kk) {
#pragma unroll
        for (int i2 = 0; i2 < 2; ++i2) {
            int chunk = t + i2 * 256;
            int row = chunk >> 2, c8 = (chunk & 3) * 8;
            *(u16x8*)&Asl[row * 40 + c8] =
                *(const u16x8*)&A[(size_t)(rowA + row) * 256 + kk * 32 + c8];
            *(u16x8*)&Bsl[row * 40 + c8] =
                *(const u16x8*)&Bt[(size_t)(colB + row) * 256 + kk * 32 + c8];
        }
        __syncthreads();
        bf16x8 af[4], bfr[4];
#pragma unroll
        for (int m = 0; m < 4; ++m)
            af[m] = *(const bf16x8*)&Asl[(wr * 64 + m * 16 + li) * 40 + g * 8];
#pragma unroll
        for (int n = 0; n < 4; ++n)
            bfr[n] = *(const bf16x8*)&Bsl[(wc * 64 + n * 16 + li) * 40 + g * 8];
#pragma unroll
        for (int m = 0; m < 4; ++m)
#pragma unroll
            for (int n = 0; n < 4; ++n)
                acc[m][n] = MFMA16(af[m], bfr[n], acc[m][n]);
        __syncthreads();
    }
#pragma unroll
    for (int m = 0; m < 4; ++m)
#pragma unroll
        for (int n = 0; n < 4; ++n) {
            int r = rowA + wr * 64 + m * 16 + g * 4;
            int c = colB + wc * 64 + n * 16 + li;
#pragma unroll
            for (int i = 0; i < 4; ++i) {
                float vv = acc[m][n][i] * scale;
                if (OUTBF)
                    ((unsigned short*)Cp)[(size_t)(r + i) * 2048 + c] = f2bf(vv);
                else
                    ((float*)Cp)[(size_t)(r + i) * 2048 + c] = vv;
            }
        }
}

// ----------------------------- attention -----------------------------------
// grid (8 qtiles, E*H=32, B=8), 256 threads. Wave w handles 16 q-rows.
// Online softmax; mask semantics identical to ref (masked logit = -1e18).
__global__ __launch_bounds__(256) void attn_kern(
        const unsigned short* __restrict__ Qp, const unsigned short* __restrict__ Kp,
        const unsigned short* __restrict__ Vp, const int* __restrict__ mask,
        unsigned short* __restrict__ CTX) {
    __shared__ unsigned short vt[64 * 32];        // V^T tile, octet-XOR swizzled
    __shared__ unsigned short p_lds[4][16 * 40];  // per-wave P tile
    const int b = blockIdx.z, eh = blockIdx.y, qt = blockIdx.x;
    const int e = eh >> 2, h = eh & 3;
    const int t = threadIdx.x, w = t >> 6, l = t & 63, li = l & 15, g = l >> 4;
    const int hoff = e * 256 + h * 64;
    const int qrow0 = qt * 64 + w * 16;

    const size_t qb = (size_t)(b * 512 + qrow0 + li) * 2048 + hoff + g * 8;
    bf16x8 q0 = *(const bf16x8*)&Qp[qb];
    bf16x8 q1 = *(const bf16x8*)&Qp[qb + 32];

    f32x4 acc[4];
#pragma unroll
    for (int c = 0; c < 4; ++c) acc[c] = (f32x4){0.f, 0.f, 0.f, 0.f};
    float m_run[4], l_run[4];
#pragma unroll
    for (int i = 0; i < 4; ++i) { m_run[i] = -3.0e38f; l_run[i] = 0.f; }

    const int sk = t >> 3, sd8 = (t & 7) * 8;   // V staging: k-row, dh octet

    for (int kt = 0; kt < 16; ++kt) {
        __syncthreads();   // prior PV reads of vt/p_lds done
        // ---- stage V^T (transpose through registers, swizzled scalar writes)
        u16x8 vv = *(const u16x8*)&Vp[(size_t)(b * 512 + kt * 32 + sk) * 2048 + hoff + sd8];
#pragma unroll
        for (int j = 0; j < 8; ++j) {
            int dh = sd8 + j;
            vt[dh * 32 + (((sk >> 3) ^ ((dh >> 3) & 3)) << 3) + (sk & 7)] = vv[j];
        }
        // ---- S = Q K^T  (16 x 32 per wave)
        f32x4 s[2];
#pragma unroll
        for (int f = 0; f < 2; ++f) {
            size_t kb = (size_t)(b * 512 + kt * 32 + f * 16 + li) * 2048 + hoff + g * 8;
            bf16x8 k0 = *(const bf16x8*)&Kp[kb];
            bf16x8 k1 = *(const bf16x8*)&Kp[kb + 32];
            f32x4 z = (f32x4){0.f, 0.f, 0.f, 0.f};
            z = MFMA16(q0, k0, z);
            z = MFMA16(q1, k1, z);
            s[f] = z;
        }
        // ---- mask (exact ref semantics)
#pragma unroll
        for (int i = 0; i < 4; ++i) {
            const int* mrow = mask + (size_t)(b * 512 + qrow0 + g * 4 + i) * 512 + kt * 32;
            if (mrow[li]) s[0][i] = -1e18f;
            if (mrow[li + 16]) s[1][i] = -1e18f;
        }
        // ---- online softmax (rows live in 16-lane groups)
        float tmax[4], p0[4], p1[4], rs[4], corr[4];
#pragma unroll
        for (int i = 0; i < 4; ++i) tmax[i] = fmaxf(s[0][i], s[1][i]);
#pragma unroll
        for (int d = 1; d < 16; d <<= 1)
#pragma unroll
            for (int i = 0; i < 4; ++i)
                tmax[i] = fmaxf(tmax[i], __shfl_xor(tmax[i], d, 64));
#pragma unroll
        for (int i = 0; i < 4; ++i) {
            float mn = fmaxf(m_run[i], tmax[i]);
            corr[i] = __expf(m_run[i] - mn);
            p0[i] = __expf(s[0][i] - mn);
            p1[i] = __expf(s[1][i] - mn);
            rs[i] = p0[i] + p1[i];
            m_run[i] = mn;
        }
#pragma unroll
        for (int d = 1; d < 16; d <<= 1)
#pragma unroll
            for (int i = 0; i < 4; ++i) rs[i] += __shfl_xor(rs[i], d, 64);
#pragma unroll
        for (int i = 0; i < 4; ++i) l_run[i] = l_run[i] * corr[i] + rs[i];
#pragma unroll
        for (int c = 0; c < 4; ++c)
#pragma unroll
            for (int i = 0; i < 4; ++i) acc[c][i] *= corr[i];
        // ---- P -> bf16 -> per-wave LDS tile
#pragma unroll
        for (int i = 0; i < 4; ++i) {
            p_lds[w][(g * 4 + i) * 40 + li] = f2bf(p0[i]);
            p_lds[w][(g * 4 + i) * 40 + 16 + li] = f2bf(p1[i]);
        }
        __syncthreads();   // vt ready for all waves; own p_lds writes ordered
        // ---- PV accumulate
        bf16x8 pa = *(const bf16x8*)&p_lds[w][li * 40 + g * 8];
#pragma unroll
        for (int c = 0; c < 4; ++c) {
            int dh = c * 16 + li;
            bf16x8 bv = *(const bf16x8*)&vt[dh * 32 + ((g ^ ((dh >> 3) & 3)) << 3)];
            acc[c] = MFMA16(pa, bv, acc[c]);
        }
    }
    // ---- normalize + store ctx [B,S,E,256] bf16
#pragma unroll
    for (int c = 0; c < 4; ++c)
#pragma unroll
        for (int i = 0; i < 4; ++i) {
            int qrow = qrow0 + g * 4 + i;
            CTX[(size_t)((b * 512 + qrow) * 8 + e) * 256 + h * 64 + c * 16 + li] =
                f2bf(acc[c][i] / l_run[i]);
        }
}

// ------------------------------- launch ------------------------------------
extern "C" void kernel_launch(void* const* d_in, const int* in_sizes, int n_in,
                              void* d_out, int out_size, void* d_ws, size_t ws_size,
                              hipStream_t stream) {
    (void)in_sizes; (void)n_in; (void)out_size; (void)ws_size;
    const float* queries = (const float*)d_in[0];
    const float* keys    = (const float*)d_in[1];
    const float* values  = (const float*)d_in[2];
    const int*   mask    = (const int*)d_in[3];
    const float* Wq = (const float*)d_in[4];
    const float* Wk = (const float*)d_in[5];
    const float* Wv = (const float*)d_in[6];
    const float* Wo = (const float*)d_in[7];

    unsigned short* Qp  = (unsigned short*)d_ws;          // [4096][2048] bf16
    unsigned short* Kp  = Qp + 4096 * 2048;
    unsigned short* Vp  = Kp + 4096 * 2048;
    unsigned short* CTX = Vp + 4096 * 2048;               // [32768][256] bf16
    unsigned short* Qbf = CTX + 32768 * 256;              // [4096][256] bf16
    unsigned short* Kbf = Qbf + 4096 * 256;
    unsigned short* Vbf = Kbf + 4096 * 256;
    unsigned short* Wqt = Vbf + 4096 * 256;               // [2048][256] bf16
    unsigned short* Wkt = Wqt + 2048 * 256;
    unsigned short* Wvt = Wkt + 2048 * 256;
    unsigned short* Wot = Wvt + 2048 * 256;

    cast_act_kern<<<dim3(1024, 1, 3), 256, 0, stream>>>(queries, keys, values, Qbf, Kbf, Vbf);
    cast_wt_kern<<<dim3(64, 8, 4), 256, 0, stream>>>(Wq, Wk, Wv, Wo, Wqt, Wkt, Wvt, Wot);
    gemm_kern<true><<<dim3(16, 32), 256, 0, stream>>>(Qbf, Wqt, Qp, 0.125f);  // *SCALE
    gemm_kern<true><<<dim3(16, 32), 256, 0, stream>>>(Kbf, Wkt, Kp, 1.0f);
    gemm_kern<true><<<dim3(16, 32), 256, 0, stream>>>(Vbf, Wvt, Vp, 1.0f);
    attn_kern<<<dim3(8, 32, 8), 256, 0, stream>>>(Qp, Kp, Vp, mask, CTX);
    gemm_kern<false><<<dim3(16, 256), 256, 0, stream>>>(CTX, Wot, d_out, 1.0f);
}

// Round 2
// 227.799 us; speedup vs baseline: 1.0224x; 1.0224x over previous
//
#include <hip/hip_runtime.h>
#include <stdint.h>

// ---------------------------------------------------------------------------
// MultiExpertMultiHeadAttention  (B=8,S=512,D=256,E=8,H=4,DH=64)
// Round 2: BK=64 GEMM, fused launches (4 total), attention l-via-MFMA +
// defer-max. Workspace usage: 77,594,624 bytes.
// ---------------------------------------------------------------------------

typedef __bf16 bf16x8 __attribute__((ext_vector_type(8)));
typedef float f32x4 __attribute__((ext_vector_type(4)));
typedef unsigned short u16x8 __attribute__((ext_vector_type(8)));
typedef unsigned short u16x4 __attribute__((ext_vector_type(4)));

#define MFMA16(a, b, c) __builtin_amdgcn_mfma_f32_16x16x32_bf16(a, b, c, 0, 0, 0)

__device__ __forceinline__ unsigned short f2bf(float x) {
    uint32_t u = __builtin_bit_cast(uint32_t, x);
    u += 0x7FFFu + ((u >> 16) & 1u);      // round-to-nearest-even
    return (unsigned short)(u >> 16);
}

// ------------------- prep: act casts + weight transpose-casts ---------------
// blocks [0,3072): activation cast (1024 per tensor)
// blocks [3072,5120): weight transpose+cast (512 per weight)
__global__ __launch_bounds__(256) void prep_kern(
        const float* __restrict__ q, const float* __restrict__ k,
        const float* __restrict__ v,
        const float* __restrict__ Wq, const float* __restrict__ Wk,
        const float* __restrict__ Wv, const float* __restrict__ Wo,
        unsigned short* __restrict__ qb, unsigned short* __restrict__ kb,
        unsigned short* __restrict__ vb, unsigned short* __restrict__ wt) {
    __shared__ float tile[32][33];
    const int x = blockIdx.x, t = threadIdx.x;
    if (x < 3072) {
        int which = x >> 10;
        const float* s = (which == 0) ? q : (which == 1) ? k : v;
        unsigned short* o = (which == 0) ? qb : (which == 1) ? kb : vb;
        int i = ((x & 1023) * 256 + t) * 4;
        float4 f = *(const float4*)&s[i];
        u16x4 r;
        r[0] = f2bf(f.x); r[1] = f2bf(f.y); r[2] = f2bf(f.z); r[3] = f2bf(f.w);
        *(u16x4*)&o[i] = r;
    } else {
        int y = x - 3072;
        int wsel = y >> 9;
        const float* W = (wsel == 0) ? Wq : (wsel == 1) ? Wk : (wsel == 2) ? Wv : Wo;
        unsigned short* T = wt + wsel * 2048 * 256;
        int rem = y & 511;
        int c0 = (rem & 63) * 32, r0 = (rem >> 6) * 32;
        int tr = t >> 3, tc = (t & 7) * 4;
        float4 f = *(const float4*)&W[(r0 + tr) * 2048 + c0 + tc];
        tile[tr][tc + 0] = f.x; tile[tr][tc + 1] = f.y;
        tile[tr][tc + 2] = f.z; tile[tr][tc + 3] = f.w;
        __syncthreads();
        u16x4 o;
        o[0] = f2bf(tile[tc + 0][tr]); o[1] = f2bf(tile[tc + 1][tr]);
        o[2] = f2bf(tile[tc + 2][tr]); o[3] = f2bf(tile[tc + 3][tr]);
        *(u16x4*)&T[(c0 + tr) * 256 + r0 + tc] = o;
    }
}

// ------------------------------- GEMM --------------------------------------
// C[M x 2048] = A[M x 256](bf16) * B (given as Bt[2048][256] bf16).
// 128x128 tile, BK=64 (4 k-iters), 256 threads (2x2 waves, 64x64 each).
// MULTI: blockIdx.z selects {Q,K,V} via base + z*stride; scale only for z==0.
template <bool OUTBF, bool MULTI>
__global__ __launch_bounds__(256) void gemm_kern(
        const unsigned short* __restrict__ Abase,
        const unsigned short* __restrict__ Btbase,
        void* __restrict__ Cbase, float scale0) {
    __shared__ unsigned short Asl[128 * 72];   // stride 72 ushorts = 144B
    __shared__ unsigned short Bsl[128 * 72];
    const int z = MULTI ? blockIdx.z : 0;
    const unsigned short* A  = Abase  + (size_t)z * 4096 * 256;
    const unsigned short* Bt = Btbase + (size_t)z * 2048 * 256;
    const float scale = (MULTI && z != 0) ? 1.0f : scale0;
    const int t = threadIdx.x, l = t & 63, w = t >> 6;
    const int li = l & 15, g = l >> 4;
    const int wr = w >> 1, wc = w & 1;
    const int rowA = blockIdx.y * 128, colB = blockIdx.x * 128;
    f32x4 acc[4][4];
#pragma unroll
    for (int m = 0; m < 4; ++m)
#pragma unroll
        for (int n = 0; n < 4; ++n) acc[m][n] = (f32x4){0.f, 0.f, 0.f, 0.f};

    for (int kk = 0; kk < 4; ++kk) {
#pragma unroll
        for (int j = 0; j < 4; ++j) {
            int chunk = t + j * 256;
            int row = chunk >> 3, c8 = (chunk & 7) * 8;
            *(u16x8*)&Asl[row * 72 + c8] =
                *(const u16x8*)&A[(size_t)(rowA + row) * 256 + kk * 64 + c8];
            *(u16x8*)&Bsl[row * 72 + c8] =
                *(const u16x8*)&Bt[(size_t)(colB + row) * 256 + kk * 64 + c8];
        }
        __syncthreads();
#pragma unroll
        for (int h = 0; h < 2; ++h) {
            bf16x8 af[4], bfr[4];
#pragma unroll
            for (int m = 0; m < 4; ++m)
                af[m] = *(const bf16x8*)&Asl[(wr * 64 + m * 16 + li) * 72 + h * 32 + g * 8];
#pragma unroll
            for (int n = 0; n < 4; ++n)
                bfr[n] = *(const bf16x8*)&Bsl[(wc * 64 + n * 16 + li) * 72 + h * 32 + g * 8];
#pragma unroll
            for (int m = 0; m < 4; ++m)
#pragma unroll
                for (int n = 0; n < 4; ++n)
                    acc[m][n] = MFMA16(af[m], bfr[n], acc[m][n]);
        }
        __syncthreads();
    }
#pragma unroll
    for (int m = 0; m < 4; ++m)
#pragma unroll
        for (int n = 0; n < 4; ++n) {
            int r = rowA + wr * 64 + m * 16 + g * 4;
            int c = colB + wc * 64 + n * 16 + li;
#pragma unroll
            for (int i = 0; i < 4; ++i) {
                float vv = acc[m][n][i] * scale;
                if (OUTBF)
                    ((unsigned short*)Cbase + (size_t)z * 4096 * 2048)
                        [(size_t)(r + i) * 2048 + c] = f2bf(vv);
                else
                    __builtin_nontemporal_store(
                        vv, &((float*)Cbase)[(size_t)(r + i) * 2048 + c]);
            }
        }
}

// ----------------------------- attention -----------------------------------
// grid (8 qtiles, E*H=32, B=8), 256 threads; wave w owns 16 q-rows.
// l accumulated via ones-column MFMA (accv[4]); defer-max with THR=8.
__global__ __launch_bounds__(256) void attn_kern(
        const unsigned short* __restrict__ Qp, const unsigned short* __restrict__ Kp,
        const unsigned short* __restrict__ Vp, const int* __restrict__ mask,
        unsigned short* __restrict__ CTX) {
    __shared__ unsigned short vt[64 * 32];        // V^T tile, octet-XOR swizzled
    __shared__ unsigned short p_lds[4][16 * 40];  // per-wave P tile
    const int b = blockIdx.z, eh = blockIdx.y, qt = blockIdx.x;
    const int e = eh >> 2, h = eh & 3;
    const int t = threadIdx.x, w = t >> 6, l = t & 63, li = l & 15, g = l >> 4;
    const int hoff = e * 256 + h * 64;
    const int qrow0 = qt * 64 + w * 16;

    const size_t qb = (size_t)(b * 512 + qrow0 + li) * 2048 + hoff + g * 8;
    bf16x8 q0 = *(const bf16x8*)&Qp[qb];
    bf16x8 q1 = *(const bf16x8*)&Qp[qb + 32];

    // ones-column fragment: lane li==0 holds 1.0 at every k element
    bf16x8 vaug;
#pragma unroll
    for (int j = 0; j < 8; ++j) vaug[j] = (li == 0) ? (__bf16)1.0f : (__bf16)0.0f;

    f32x4 accv[5];
#pragma unroll
    for (int c = 0; c < 5; ++c) accv[c] = (f32x4){0.f, 0.f, 0.f, 0.f};
    float m_run[4];
#pragma unroll
    for (int i = 0; i < 4; ++i) m_run[i] = -3.0e38f;

    const int sk = t >> 3, sd8 = (t & 7) * 8;   // V staging: k-row, dh octet

    for (int kt = 0; kt < 16; ++kt) {
        __syncthreads();   // prior PV reads of vt/p_lds done
        // ---- stage V^T (transpose through registers, swizzled scalar writes)
        u16x8 vv = *(const u16x8*)&Vp[(size_t)(b * 512 + kt * 32 + sk) * 2048 + hoff + sd8];
#pragma unroll
        for (int j = 0; j < 8; ++j) {
            int dh = sd8 + j;
            vt[dh * 32 + (((sk >> 3) ^ ((dh >> 3) & 3)) << 3) + (sk & 7)] = vv[j];
        }
        // ---- S = Q K^T  (16 x 32 per wave)
        f32x4 s[2];
#pragma unroll
        for (int f = 0; f < 2; ++f) {
            size_t kb = (size_t)(b * 512 + kt * 32 + f * 16 + li) * 2048 + hoff + g * 8;
            bf16x8 k0 = *(const bf16x8*)&Kp[kb];
            bf16x8 k1 = *(const bf16x8*)&Kp[kb + 32];
            f32x4 zz = (f32x4){0.f, 0.f, 0.f, 0.f};
            zz = MFMA16(q0, k0, zz);
            zz = MFMA16(q1, k1, zz);
            s[f] = zz;
        }
        // ---- mask (exact ref semantics: masked logit = -1e18)
#pragma unroll
        for (int i = 0; i < 4; ++i) {
            const int* mrow = mask + (size_t)(b * 512 + qrow0 + g * 4 + i) * 512 + kt * 32;
            if (mrow[li]) s[0][i] = -1e18f;
            if (mrow[li + 16]) s[1][i] = -1e18f;
        }
        // ---- tile max (16-lane butterfly per row)
        float tmax[4];
#pragma unroll
        for (int i = 0; i < 4; ++i) tmax[i] = fmaxf(s[0][i], s[1][i]);
#pragma unroll
        for (int d = 1; d < 16; d <<= 1)
#pragma unroll
            for (int i = 0; i < 4; ++i)
                tmax[i] = fmaxf(tmax[i], __shfl_xor(tmax[i], d, 64));
        // ---- defer-max: rescale only when some row grew past THR=8
        bool need = false;
#pragma unroll
        for (int i = 0; i < 4; ++i) need |= (tmax[i] > m_run[i] + 8.0f);
        if (__any(need)) {
#pragma unroll
            for (int i = 0; i < 4; ++i) {
                float mn = fmaxf(m_run[i], tmax[i]);
                float corr = __expf(m_run[i] - mn);
                m_run[i] = mn;
#pragma unroll
                for (int c = 0; c < 5; ++c) accv[c][i] *= corr;
            }
        }
        // ---- P = exp(S - m_run) -> bf16 -> per-wave LDS tile
#pragma unroll
        for (int i = 0; i < 4; ++i) {
            p_lds[w][(g * 4 + i) * 40 + li] = f2bf(__expf(s[0][i] - m_run[i]));
            p_lds[w][(g * 4 + i) * 40 + 16 + li] = f2bf(__expf(s[1][i] - m_run[i]));
        }
        __syncthreads();   // vt ready for all waves; p_lds drained (lgkmcnt 0)
        // ---- PV accumulate (+ ones column into accv[4] = running l)
        bf16x8 pa = *(const bf16x8*)&p_lds[w][li * 40 + g * 8];
#pragma unroll
        for (int c = 0; c < 4; ++c) {
            int dh = c * 16 + li;
            bf16x8 bv = *(const bf16x8*)&vt[dh * 32 + ((g ^ ((dh >> 3) & 3)) << 3)];
            accv[c] = MFMA16(pa, bv, accv[c]);
        }
        accv[4] = MFMA16(pa, vaug, accv[4]);
    }
    // ---- normalize + store ctx [B,S,E,256] bf16
#pragma unroll
    for (int i = 0; i < 4; ++i) {
        float l_i = __shfl(accv[4][i], (l & 48), 64);   // broadcast from li==0 lane
        float inv = 1.0f / l_i;
        int qrow = qrow0 + g * 4 + i;
#pragma unroll
        for (int c = 0; c < 4; ++c) {
            CTX[(size_t)((b * 512 + qrow) * 8 + e) * 256 + h * 64 + c * 16 + li] =
                f2bf(accv[c][i] * inv);
        }
    }
}

// ------------------------------- launch ------------------------------------
extern "C" void kernel_launch(void* const* d_in, const int* in_sizes, int n_in,
                              void* d_out, int out_size, void* d_ws, size_t ws_size,
                              hipStream_t stream) {
    (void)in_sizes; (void)n_in; (void)out_size; (void)ws_size;
    const float* queries = (const float*)d_in[0];
    const float* keys    = (const float*)d_in[1];
    const float* values  = (const float*)d_in[2];
    const int*   mask    = (const int*)d_in[3];
    const float* Wq = (const float*)d_in[4];
    const float* Wk = (const float*)d_in[5];
    const float* Wv = (const float*)d_in[6];
    const float* Wo = (const float*)d_in[7];

    unsigned short* Qp  = (unsigned short*)d_ws;          // [3][4096][2048] bf16 (Q,K,V)
    unsigned short* CTX = Qp + (size_t)3 * 4096 * 2048;   // [32768][256] bf16
    unsigned short* Qbf = CTX + (size_t)32768 * 256;      // [3][4096][256] bf16
    unsigned short* Wt  = Qbf + (size_t)3 * 4096 * 256;   // [4][2048][256] bf16

    prep_kern<<<dim3(5120), 256, 0, stream>>>(queries, keys, values,
                                              Wq, Wk, Wv, Wo,
                                              Qbf, Qbf + 4096 * 256, Qbf + 2 * 4096 * 256, Wt);
    gemm_kern<true, true><<<dim3(16, 32, 3), 256, 0, stream>>>(Qbf, Wt, Qp, 0.125f);
    attn_kern<<<dim3(8, 32, 8), 256, 0, stream>>>(Qp, Qp + (size_t)4096 * 2048,
                                                  Qp + (size_t)2 * 4096 * 2048, mask, CTX);
    gemm_kern<false, false><<<dim3(16, 256), 256, 0, stream>>>(
        CTX, Wt + (size_t)3 * 2048 * 256, d_out, 1.0f);
}